// Round 1
// baseline (1319.229 us; speedup 1.0000x reference)
//
#include <hip/hip_runtime.h>
#include <cmath>

#define GI_STRIDE (258*192)            // one gi table: 258 tokens x 192 gate-rows
#define FILM_OFF  (2*GI_STRIDE)        // 99072 floats
#define TOTAL_PRE (FILM_OFF + 256*256) // 164608 floats = 643*256

#define B_TOT   1024
#define L_MAX   256
#define SOS_TOK 257
#define EOS_TOK 256

// ---------------------------------------------------------------------------
// Prologue: precompute gi tables (token_embed @ w_ih.T + b_ih for all 258
// tokens, both GRUs) and the FiLM table tanh(step_table[t] @ film_w.T + film_b)
// for all 256 steps. Written to d_ws.
// ---------------------------------------------------------------------------
__global__ __launch_bounds__(256) void aag_precompute(
    const float* __restrict__ token_embed,
    const float* __restrict__ step_table,
    const float* __restrict__ w_ih_f, const float* __restrict__ b_ih_f,
    const float* __restrict__ w_ih_b, const float* __restrict__ b_ih_b,
    const float* __restrict__ film_w, const float* __restrict__ film_b,
    float* __restrict__ ws)
{
    int idx = blockIdx.x * 256 + threadIdx.x;
    if (idx < FILM_OFF) {
        int m     = idx / GI_STRIDE;
        int rem   = idx - m * GI_STRIDE;
        int token = rem / 192;
        int r     = rem - token * 192;
        const float* wih = (m ? w_ih_b : w_ih_f) + r * 64;
        const float* te  = token_embed + token * 64;
        float acc = (m ? b_ih_b : b_ih_f)[r];
        #pragma unroll 8
        for (int k = 0; k < 64; ++k) acc += te[k] * wih[k];
        ws[idx] = acc;
    } else if (idx < TOTAL_PRE) {
        int q  = idx - FILM_OFF;
        int tt = q >> 8, j = q & 255;
        const float* st = step_table + tt * 16;
        const float* fw = film_w + j * 16;
        float acc = film_b[j];
        #pragma unroll
        for (int s = 0; s < 16; ++s) acc += st[s] * fw[s];
        ws[idx] = tanhf(acc);
    }
}

// ---------------------------------------------------------------------------
// Main persistent kernel: 256 blocks x 512 threads, 4 batch elements/block,
// full 256-step decode loop. GRU-hh + decoder weights live in registers.
// ---------------------------------------------------------------------------
__global__ __launch_bounds__(512, 2) void aag_decode(
    const int* __restrict__ step_ptr,
    const float* __restrict__ w_hh_f, const float* __restrict__ b_hh_f,
    const float* __restrict__ w_hh_b, const float* __restrict__ b_hh_b,
    const float* __restrict__ dec_w, const float* __restrict__ dec_b,
    const float* __restrict__ ws,
    float* __restrict__ out)
{
    __shared__ __align__(16) float hbuf[2][4][64];   // h state (pre-FiLM)
    __shared__ __align__(16) float ghL[2][4][192];   // h @ w_hh.T + b_hh
    __shared__ __align__(16) float hsL[4][128];      // FiLMed concat state
    __shared__ __align__(16) float plL[4][520];      // decoder partial sums
    __shared__ __align__(16) float eosW[128];        // dec_w row 256
    __shared__ unsigned int selL[4][9];
    __shared__ int inpL[4];
    __shared__ int doneL[4];

    const int tid  = threadIdx.x;
    const int wave = tid >> 6;
    const int lane = tid & 63;

    // exponential-decay temperature, matching host double math
    float invT;
    {
        int step = step_ptr[0];
        if (step < 0) step = 0;
        double T = 0.2 + 2.3 * exp(-(0.6931471805599453 / 3000.0) * (double)step);
        if (T < 1e-6) T = 1e-6;
        invT = (float)(1.0 / T);
    }

    // ---- persistent weights in registers ----
    // GRU: 384 rows (2 matrices x 192) -> lanes 0..47 of each of 8 waves
    const bool hasG = (lane < 48);
    const int  grow = wave * 48 + lane;          // [0,384) when hasG
    const int  gm   = (grow >= 192) ? 1 : 0;
    const int  gr   = grow - gm * 192;
    float wg[64];
    float bG = 0.f;
    if (hasG) {
        const float* whh = (gm ? w_hh_b : w_hh_f) + gr * 64;
        #pragma unroll
        for (int k = 0; k < 64; ++k) wg[k] = whh[k];
        bG = (gm ? b_hh_b : b_hh_f)[gr];
    }
    // decoder: rows 0..255 split into half-rows, one per thread
    const int dro = tid >> 1, dhalf = tid & 1;
    float wd[64];
    {
        const float* dw = dec_w + dro * 128 + dhalf * 64;
        #pragma unroll
        for (int k = 0; k < 64; ++k) wd[k] = dw[k];
    }
    // softmax-phase dec_b registers (waves 0..3 only)
    float db0 = 0.f, db1 = 0.f, db2 = 0.f, db3 = 0.f, db4 = 0.f;
    if (tid < 256) {
        const int l = lane;
        db0 = dec_b[l]; db1 = dec_b[64 + l]; db2 = dec_b[128 + l]; db3 = dec_b[192 + l];
        if (l == 0) db4 = dec_b[256];
    }

    // ---- init state ----
    ((float*)hbuf)[tid] = 0.f;                       // 512 floats = all of hbuf
    if (tid < 128) eosW[tid] = dec_w[256 * 128 + tid];
    if (tid < 36)  ((unsigned int*)selL)[tid] = 0u;
    if (tid < 4)   { inpL[tid] = SOS_TOK; doneL[tid] = 0; }
    __syncthreads();

    const int ge  = tid >> 7;       // gate phase: element
    const int gj  = tid & 127;      // hs index
    const int gmm = gj >> 6;        // which GRU
    const int gii = gj & 63;        // hidden index

    const int b0 = blockIdx.x * 4;
    float* __restrict__ out_act = out;
    float* __restrict__ out_lp  = out + B_TOT * L_MAX;
    float* __restrict__ out_val = out + 2 * B_TOT * L_MAX;

    for (int t = 0; t < L_MAX; ++t) {
        // gate-phase operand loads: issued now, consumed after B1 (latency
        // hides under the GRU matvec)
        const int tok = inpL[ge];
        const float* girow = ws + gmm * GI_STRIDE + tok * 192;
        const float gi_r = girow[gii];
        const float gi_z = girow[64 + gii];
        const float gi_n = girow[128 + gii];
        const float* fr = ws + FILM_OFF + t * 256;
        const float ga = fr[gmm * 64 + gii];
        const float be = fr[128 + gmm * 64 + gii];

        // ---- GRU hidden matvec: gh = h @ w_hh.T + b_hh ----
        if (hasG) {
            float a0 = bG, a1 = bG, a2 = bG, a3 = bG;
            #pragma unroll
            for (int kk = 0; kk < 64; kk += 4) {
                const float4 h0 = *(const float4*)&hbuf[gm][0][kk];
                const float4 h1 = *(const float4*)&hbuf[gm][1][kk];
                const float4 h2 = *(const float4*)&hbuf[gm][2][kk];
                const float4 h3 = *(const float4*)&hbuf[gm][3][kk];
                a0 += h0.x*wg[kk] + h0.y*wg[kk+1] + h0.z*wg[kk+2] + h0.w*wg[kk+3];
                a1 += h1.x*wg[kk] + h1.y*wg[kk+1] + h1.z*wg[kk+2] + h1.w*wg[kk+3];
                a2 += h2.x*wg[kk] + h2.y*wg[kk+1] + h2.z*wg[kk+2] + h2.w*wg[kk+3];
                a3 += h3.x*wg[kk] + h3.y*wg[kk+1] + h3.z*wg[kk+2] + h3.w*wg[kk+3];
            }
            ghL[gm][0][gr] = a0; ghL[gm][1][gr] = a1;
            ghL[gm][2][gr] = a2; ghL[gm][3][gr] = a3;
        }
        __syncthreads();   // B1: gh ready

        // ---- gate phase: h update + FiLM ----
        {
            const float hr = ghL[gmm][ge][gii];
            const float hz = ghL[gmm][ge][64 + gii];
            const float hn = ghL[gmm][ge][128 + gii];
            const float hp = hbuf[gmm][ge][gii];
            const float r  = 1.f / (1.f + expf(-(gi_r + hr)));
            const float z  = 1.f / (1.f + expf(-(gi_z + hz)));
            const float n  = tanhf(gi_n + r * hn);
            const float h2 = (1.f - z) * n + z * hp;
            hbuf[gmm][ge][gii] = h2;                       // carried state: pre-FiLM
            hsL[ge][gmm * 64 + gii] = h2 * (1.f + ga) + be;
        }
        __syncthreads();   // B2: hs ready

        // ---- decoder matvec (half-rows; EOS row in 16-wide chunks) ----
        {
            float d0 = 0.f, d1 = 0.f, d2 = 0.f, d3 = 0.f;
            const int base = dhalf * 64;
            #pragma unroll
            for (int kk = 0; kk < 64; kk += 4) {
                const float4 s0 = *(const float4*)&hsL[0][base + kk];
                const float4 s1 = *(const float4*)&hsL[1][base + kk];
                const float4 s2 = *(const float4*)&hsL[2][base + kk];
                const float4 s3 = *(const float4*)&hsL[3][base + kk];
                d0 += s0.x*wd[kk] + s0.y*wd[kk+1] + s0.z*wd[kk+2] + s0.w*wd[kk+3];
                d1 += s1.x*wd[kk] + s1.y*wd[kk+1] + s1.z*wd[kk+2] + s1.w*wd[kk+3];
                d2 += s2.x*wd[kk] + s2.y*wd[kk+1] + s2.z*wd[kk+2] + s2.w*wd[kk+3];
                d3 += s3.x*wd[kk] + s3.y*wd[kk+1] + s3.z*wd[kk+2] + s3.w*wd[kk+3];
            }
            plL[0][tid] = d0; plL[1][tid] = d1; plL[2][tid] = d2; plL[3][tid] = d3;
            if (tid >= 504) {
                const int c = tid - 504;
                float e0 = 0.f, e1 = 0.f, e2 = 0.f, e3 = 0.f;
                #pragma unroll
                for (int k = 0; k < 16; ++k) {
                    const float w = eosW[c * 16 + k];
                    e0 += hsL[0][c*16+k] * w; e1 += hsL[1][c*16+k] * w;
                    e2 += hsL[2][c*16+k] * w; e3 += hsL[3][c*16+k] * w;
                }
                plL[0][512+c] = e0; plL[1][512+c] = e1;
                plL[2][512+c] = e2; plL[3][512+c] = e3;
            }
        }
        __syncthreads();   // B3: partial logits ready

        // ---- masked argmax + logprob + state update: wave e <-> element e ----
        if (tid < 256) {
            const int e = wave;
            const int l = lane;
            const float2 p0 = *(const float2*)&plL[e][2 * l];
            const float2 p1 = *(const float2*)&plL[e][2 * (64 + l)];
            const float2 p2 = *(const float2*)&plL[e][2 * (128 + l)];
            const float2 p3 = *(const float2*)&plL[e][2 * (192 + l)];
            const float u0 = p0.x + p0.y + db0;
            const float u1 = p1.x + p1.y + db1;
            const float u2 = p2.x + p2.y + db2;
            const float u3 = p3.x + p3.y + db3;
            const int w = l >> 5, sh = l & 31;
            const bool m0 = (selL[e][w]     >> sh) & 1;
            const bool m1 = (selL[e][2 + w] >> sh) & 1;
            const bool m2 = (selL[e][4 + w] >> sh) & 1;
            const bool m3 = (selL[e][6 + w] >> sh) & 1;
            // local argmax, ascending index, strict > keeps first-max tiebreak
            float mv = m0 ? -INFINITY : u0;
            int   mi = l;
            { const float v = m1 ? -INFINITY : u1; if (v > mv) { mv = v; mi = 64 + l; } }
            { const float v = m2 ? -INFINITY : u2; if (v > mv) { mv = v; mi = 128 + l; } }
            { const float v = m3 ? -INFINITY : u3; if (v > mv) { mv = v; mi = 192 + l; } }
            float u4 = 0.f; bool m4 = true;
            if (l == 0) {
                float s = db4;
                #pragma unroll
                for (int c = 0; c < 8; ++c) s += plL[e][512 + c];
                u4 = s;
                m4 = (selL[e][8] & 1u) != 0u;
                const float v = m4 ? -INFINITY : u4;
                if (v > mv) { mv = v; mi = 256; }
            }
            // butterfly: max value, smallest index on ties (jnp.argmax semantics)
            #pragma unroll
            for (int off = 1; off < 64; off <<= 1) {
                const float ov = __shfl_xor(mv, off);
                const int   oi = __shfl_xor(mi, off);
                if (ov > mv || (ov == mv && oi < mi)) { mv = ov; mi = oi; }
            }
            // sum of exp((u - M)/T) over unmasked -> lp = -log(S)
            float S = 0.f;
            if (!m0) S += expf((u0 - mv) * invT);
            if (!m1) S += expf((u1 - mv) * invT);
            if (!m2) S += expf((u2 - mv) * invT);
            if (!m3) S += expf((u3 - mv) * invT);
            if (!m4) S += expf((u4 - mv) * invT);
            #pragma unroll
            for (int off = 1; off < 64; off <<= 1) S += __shfl_xor(S, off);
            if (l == 0) {
                const int a = mi;
                const float lp = -logf(S);
                const int wasdone = doneL[e];
                const int b = b0 + e;
                out_act[b * L_MAX + t] = (float)a;
                out_lp [b * L_MAX + t] = wasdone ? 0.f : lp;
                out_val[b * L_MAX + t] = wasdone ? 0.f : 1.f;
                selL[e][a >> 5] |= (1u << (a & 31));
                inpL[e] = a;
                if (a == EOS_TOK) doneL[e] = 1;
            }
        }
        __syncthreads();   // B4: sel/inp/done updated for next step
    }
}

extern "C" void kernel_launch(void* const* d_in, const int* in_sizes, int n_in,
                              void* d_out, int out_size, void* d_ws, size_t ws_size,
                              hipStream_t stream)
{
    const int*   step        = (const int*)  d_in[0];
    const float* token_embed = (const float*)d_in[2];
    const float* step_table  = (const float*)d_in[3];
    const float* w_ih_f = (const float*)d_in[4];
    const float* w_hh_f = (const float*)d_in[5];
    const float* b_ih_f = (const float*)d_in[6];
    const float* b_hh_f = (const float*)d_in[7];
    const float* w_ih_b = (const float*)d_in[8];
    const float* w_hh_b = (const float*)d_in[9];
    const float* b_ih_b = (const float*)d_in[10];
    const float* b_hh_b = (const float*)d_in[11];
    const float* film_w = (const float*)d_in[12];
    const float* film_b = (const float*)d_in[13];
    const float* dec_w  = (const float*)d_in[14];
    const float* dec_b  = (const float*)d_in[15];
    float* ws   = (float*)d_ws;
    float* outp = (float*)d_out;

    aag_precompute<<<TOTAL_PRE / 256, 256, 0, stream>>>(
        token_embed, step_table, w_ih_f, b_ih_f, w_ih_b, b_ih_b,
        film_w, film_b, ws);
    aag_decode<<<256, 512, 0, stream>>>(
        step, w_hh_f, b_hh_f, w_hh_b, b_hh_b, dec_w, dec_b, ws, outp);
}

// Round 2
// 1166.848 us; speedup vs baseline: 1.1306x; 1.1306x over previous
//
#include <hip/hip_runtime.h>
#include <cmath>

#define GI_STRIDE (258*192)            // one gi table: 258 tokens x 192 gate-rows
#define FILM_OFF  (2*GI_STRIDE)        // 99072 floats
#define TOTAL_PRE (FILM_OFF + 256*256) // 164608 floats = 643*256

#define B_TOT   1024
#define L_MAX   256
#define SOS_TOK 257
#define EOS_TOK 256

// ---------------------------------------------------------------------------
// Prologue: precompute gi tables (token_embed @ w_ih.T + b_ih for all 258
// tokens, both GRUs) and the FiLM table tanh(step_table[t] @ film_w.T + film_b)
// for all 256 steps. Written to d_ws.
// ---------------------------------------------------------------------------
__global__ __launch_bounds__(256) void aag_precompute(
    const float* __restrict__ token_embed,
    const float* __restrict__ step_table,
    const float* __restrict__ w_ih_f, const float* __restrict__ b_ih_f,
    const float* __restrict__ w_ih_b, const float* __restrict__ b_ih_b,
    const float* __restrict__ film_w, const float* __restrict__ film_b,
    float* __restrict__ ws)
{
    int idx = blockIdx.x * 256 + threadIdx.x;
    if (idx < FILM_OFF) {
        int m     = idx / GI_STRIDE;
        int rem   = idx - m * GI_STRIDE;
        int token = rem / 192;
        int r     = rem - token * 192;
        const float* wih = (m ? w_ih_b : w_ih_f) + r * 64;
        const float* te  = token_embed + token * 64;
        float acc = (m ? b_ih_b : b_ih_f)[r];
        #pragma unroll 8
        for (int k = 0; k < 64; ++k) acc += te[k] * wih[k];
        ws[idx] = acc;
    } else if (idx < TOTAL_PRE) {
        int q  = idx - FILM_OFF;
        int tt = q >> 8, j = q & 255;
        const float* st = step_table + tt * 16;
        const float* fw = film_w + j * 16;
        float acc = film_b[j];
        #pragma unroll
        for (int s = 0; s < 16; ++s) acc += st[s] * fw[s];
        ws[idx] = tanhf(acc);
    }
}

#define DOT4(acc, s, w) acc += (s).x*(w).x + (s).y*(w).y + (s).z*(w).z + (s).w*(w).w

// ---------------------------------------------------------------------------
// Main persistent kernel: 256 blocks x 512 threads, 4 batch elements/block,
// 2-barrier ring:
//   P1: softmax(t-1) [replicated per wave pair, state in registers] + gate(t)
//   P2: decoder(t) + GRU matvec(t+1) merged; film(t+1) prefetch; EOS partials
// ---------------------------------------------------------------------------
__global__ __launch_bounds__(512)
__attribute__((amdgpu_waves_per_eu(2, 2)))
void aag_decode(
    const int* __restrict__ step_ptr,
    const float* __restrict__ w_hh_f, const float* __restrict__ b_hh_f,
    const float* __restrict__ w_hh_b, const float* __restrict__ b_hh_b,
    const float* __restrict__ dec_w, const float* __restrict__ dec_b,
    const float* __restrict__ ws,
    float* __restrict__ out)
{
    __shared__ __align__(16) float hbuf[2][4][64];   // h state (pre-FiLM)
    __shared__ __align__(16) float ghL[2][4][192];   // h @ w_hh.T + b_hh
    __shared__ __align__(16) float hsL[4][128];      // FiLMed concat state
    __shared__ __align__(16) float plL[2][4][256];   // decoder half-row sums
    __shared__ float eosP[4];                        // EOS-row logits (no bias)

    const int tid = threadIdx.x;
    const int wv  = tid >> 6;
    const int ln  = tid & 63;
    const int e   = wv >> 1;      // element this wave serves (softmax + gate)
    const int m   = wv & 1;       // GRU id this wave serves in gate phase

    // exponential-decay temperature, matching host double math
    float invT;
    {
        int step = step_ptr[0];
        if (step < 0) step = 0;
        double T = 0.2 + 2.3 * exp(-(0.6931471805599453 / 3000.0) * (double)step);
        if (T < 1e-6) T = 1e-6;
        invT = (float)(1.0 / T);
    }

    // ---- persistent weights in registers ----
    // GRU rows: lanes 0..47 of each wave own one of 384 rows (wave-uniform gm)
    const bool hasG = (ln < 48);
    const int  grow = wv * 48 + (hasG ? ln : 0);
    const int  gm   = (grow >= 192) ? 1 : 0;
    const int  gr   = grow - gm * 192;
    float4 wgv[16];
    float  bG;
    {
        const float* whh = (gm ? w_hh_b : w_hh_f) + gr * 64;
        #pragma unroll
        for (int j = 0; j < 16; ++j) wgv[j] = ((const float4*)whh)[j];
        bG = (gm ? b_hh_b : b_hh_f)[gr];
    }
    // decoder: wave-uniform half split (threads 0-255 half 0, 256-511 half 1)
    const int dh  = tid >> 8;
    const int dro = tid & 255;
    float4 wdv[16];
    {
        const float* dw = dec_w + dro * 128 + dh * 64;
        #pragma unroll
        for (int j = 0; j < 16; ++j) wdv[j] = ((const float4*)dw)[j];
    }
    // EOS row chunks: threads 496..511 (wave 7, GRU-idle lanes)
    float4 ew0 = {0,0,0,0}, ew1 = {0,0,0,0};
    if (tid >= 496) {
        const float* p = dec_w + 256 * 128 + (tid - 496) * 8;
        ew0 = ((const float4*)p)[0];
        ew1 = ((const float4*)p)[1];
    }
    // dec_b registers (used by softmax, every wave)
    const float db0 = dec_b[ln], db1 = dec_b[64 + ln];
    const float db2 = dec_b[128 + ln], db3 = dec_b[192 + ln];
    const float db4 = (ln == 0) ? dec_b[256] : 0.f;

    // ---- init ----
    ((float*)hbuf)[tid] = 0.f;                      // 512 floats = all of hbuf
    if (hasG) {                                     // gh(0) = bias (h(-1) = 0)
        ghL[gm][0][gr] = bG; ghL[gm][1][gr] = bG;
        ghL[gm][2][gr] = bG; ghL[gm][3][gr] = bG;
    }

    // per-wave register state (replicated on wave pairs, deterministic)
    bool s0m = false, s1m = false, s2m = false, s3m = false, s4m = false;
    bool done = false;

    // prefetch film(0) and gi(SOS)
    const float* filmT = ws + FILM_OFF;
    const float* giT   = ws + m * GI_STRIDE;
    float ga = filmT[m * 64 + ln];
    float be = filmT[128 + m * 64 + ln];
    float gi_r = giT[SOS_TOK * 192 + ln];
    float gi_z = giT[SOS_TOK * 192 + 64 + ln];
    float gi_n = giT[SOS_TOK * 192 + 128 + ln];

    const int b0 = blockIdx.x * 4;
    float* __restrict__ out_act = out;
    float* __restrict__ out_lp  = out + B_TOT * L_MAX;
    float* __restrict__ out_val = out + 2 * B_TOT * L_MAX;

    __syncthreads();   // ghL / hbuf init visible

    for (int t = 0; t <= L_MAX; ++t) {
        // ================= P1: softmax(t-1) + gate(t) =================
        if (t > 0) {
            const float u0 = plL[0][e][ln]       + plL[1][e][ln]       + db0;
            const float u1 = plL[0][e][64 + ln]  + plL[1][e][64 + ln]  + db1;
            const float u2 = plL[0][e][128 + ln] + plL[1][e][128 + ln] + db2;
            const float u3 = plL[0][e][192 + ln] + plL[1][e][192 + ln] + db3;
            float mv = s0m ? -INFINITY : u0;
            int   mi = ln;
            { const float v = s1m ? -INFINITY : u1; if (v > mv) { mv = v; mi = 64 + ln; } }
            { const float v = s2m ? -INFINITY : u2; if (v > mv) { mv = v; mi = 128 + ln; } }
            { const float v = s3m ? -INFINITY : u3; if (v > mv) { mv = v; mi = 192 + ln; } }
            float u4 = 0.f;
            if (ln == 0) {
                u4 = eosP[e] + db4;
                const float v = s4m ? -INFINITY : u4;
                if (v > mv) { mv = v; mi = 256; }
            }
            // butterfly: max value, smallest index on ties (jnp.argmax semantics)
            #pragma unroll
            for (int off = 1; off < 64; off <<= 1) {
                const float ov = __shfl_xor(mv, off);
                const int   oi = __shfl_xor(mi, off);
                if (ov > mv || (ov == mv && oi < mi)) { mv = ov; mi = oi; }
            }
            const int a = mi;
            // issue gi loads for the next gate ASAP (L2 latency hides under exp sum)
            {
                const float* gp = giT + a * 192;
                gi_r = gp[ln]; gi_z = gp[64 + ln]; gi_n = gp[128 + ln];
            }
            // softmax denominator
            float S = 0.f;
            if (!s0m) S += expf((u0 - mv) * invT);
            if (!s1m) S += expf((u1 - mv) * invT);
            if (!s2m) S += expf((u2 - mv) * invT);
            if (!s3m) S += expf((u3 - mv) * invT);
            if (ln == 0 && !s4m) S += expf((u4 - mv) * invT);
            #pragma unroll
            for (int off = 1; off < 64; off <<= 1) S += __shfl_xor(S, off);
            // state update (registers, replicated consistently on wave pairs)
            const bool wasdone = done;
            if (a == EOS_TOK) done = true;
            if ((a & 63) == ln) {
                if (a < 64) s0m = true; else if (a < 128) s1m = true;
                else if (a < 192) s2m = true; else if (a < 256) s3m = true;
                else s4m = true;
            }
            if (ln == 0 && m == 0) {
                const int b = b0 + e;
                out_act[b * L_MAX + (t - 1)] = (float)a;
                out_lp [b * L_MAX + (t - 1)] = wasdone ? 0.f : -logf(S);
                out_val[b * L_MAX + (t - 1)] = wasdone ? 0.f : 1.f;
            }
        }
        if (t == L_MAX) break;

        // ---- gate(t): thread (m, e, ln) updates one hidden unit ----
        {
            const float hr = ghL[m][e][ln];
            const float hz = ghL[m][e][64 + ln];
            const float hn = ghL[m][e][128 + ln];
            const float hp = hbuf[m][e][ln];
            const float r  = 1.f / (1.f + expf(-(gi_r + hr)));
            const float z  = 1.f / (1.f + expf(-(gi_z + hz)));
            const float n  = tanhf(gi_n + r * hn);
            const float h2 = (1.f - z) * n + z * hp;
            hbuf[m][e][ln] = h2;
            hsL[e][m * 64 + ln] = h2 * (1.f + ga) + be;
        }
        __syncthreads();   // B1: hbuf(t), hsL(t) ready

        // ================= P2: decoder(t) + GRU matvec(t+1) =================
        // film prefetch for t+1 (register, consumed next P1)
        {
            const int tn = (t + 1 < L_MAX) ? t + 1 : L_MAX - 1;
            ga = filmT[tn * 256 + m * 64 + ln];
            be = filmT[tn * 256 + 128 + m * 64 + ln];
        }
        // decoder half-rows (broadcast hsL reads: dh is wave-uniform)
        {
            float d0 = 0.f, d1 = 0.f, d2 = 0.f, d3 = 0.f;
            const int hb = dh * 64;
            #pragma unroll
            for (int j = 0; j < 16; ++j) {
                const float4 x0 = *(const float4*)&hsL[0][hb + 4 * j];
                const float4 x1 = *(const float4*)&hsL[1][hb + 4 * j];
                const float4 x2 = *(const float4*)&hsL[2][hb + 4 * j];
                const float4 x3 = *(const float4*)&hsL[3][hb + 4 * j];
                const float4 w  = wdv[j];
                DOT4(d0, x0, w); DOT4(d1, x1, w);
                DOT4(d2, x2, w); DOT4(d3, x3, w);
            }
            plL[dh][0][dro] = d0; plL[dh][1][dro] = d1;
            plL[dh][2][dro] = d2; plL[dh][3][dro] = d3;
        }
        // GRU hidden matvec for step t+1 (broadcast hbuf reads)
        if (hasG) {
            float a0 = bG, a1 = bG, a2 = bG, a3 = bG;
            #pragma unroll
            for (int j = 0; j < 16; ++j) {
                const float4 x0 = *(const float4*)&hbuf[gm][0][4 * j];
                const float4 x1 = *(const float4*)&hbuf[gm][1][4 * j];
                const float4 x2 = *(const float4*)&hbuf[gm][2][4 * j];
                const float4 x3 = *(const float4*)&hbuf[gm][3][4 * j];
                const float4 w  = wgv[j];
                DOT4(a0, x0, w); DOT4(a1, x1, w);
                DOT4(a2, x2, w); DOT4(a3, x3, w);
            }
            ghL[gm][0][gr] = a0; ghL[gm][1][gr] = a1;
            ghL[gm][2][gr] = a2; ghL[gm][3][gr] = a3;
        }
        // EOS row partials: threads 496..511, 8-wide chunks + 16-lane butterfly
        if (tid >= 496) {
            const int c = tid - 496;
            float t0, t1, t2, t3;
            {
                const float4 p0 = *(const float4*)&hsL[0][8 * c];
                const float4 p1 = *(const float4*)&hsL[0][8 * c + 4];
                t0 = p0.x*ew0.x + p0.y*ew0.y + p0.z*ew0.z + p0.w*ew0.w
                   + p1.x*ew1.x + p1.y*ew1.y + p1.z*ew1.z + p1.w*ew1.w;
            }
            {
                const float4 p0 = *(const float4*)&hsL[1][8 * c];
                const float4 p1 = *(const float4*)&hsL[1][8 * c + 4];
                t1 = p0.x*ew0.x + p0.y*ew0.y + p0.z*ew0.z + p0.w*ew0.w
                   + p1.x*ew1.x + p1.y*ew1.y + p1.z*ew1.z + p1.w*ew1.w;
            }
            {
                const float4 p0 = *(const float4*)&hsL[2][8 * c];
                const float4 p1 = *(const float4*)&hsL[2][8 * c + 4];
                t2 = p0.x*ew0.x + p0.y*ew0.y + p0.z*ew0.z + p0.w*ew0.w
                   + p1.x*ew1.x + p1.y*ew1.y + p1.z*ew1.z + p1.w*ew1.w;
            }
            {
                const float4 p0 = *(const float4*)&hsL[3][8 * c];
                const float4 p1 = *(const float4*)&hsL[3][8 * c + 4];
                t3 = p0.x*ew0.x + p0.y*ew0.y + p0.z*ew0.z + p0.w*ew0.w
                   + p1.x*ew1.x + p1.y*ew1.y + p1.z*ew1.z + p1.w*ew1.w;
            }
            #pragma unroll
            for (int off = 1; off < 16; off <<= 1) {
                t0 += __shfl_xor(t0, off); t1 += __shfl_xor(t1, off);
                t2 += __shfl_xor(t2, off); t3 += __shfl_xor(t3, off);
            }
            if (c == 0) { eosP[0] = t0; eosP[1] = t1; eosP[2] = t2; eosP[3] = t3; }
        }
        __syncthreads();   // B2: plL(t), eosP(t), ghL(t+1) ready
    }
}

extern "C" void kernel_launch(void* const* d_in, const int* in_sizes, int n_in,
                              void* d_out, int out_size, void* d_ws, size_t ws_size,
                              hipStream_t stream)
{
    const int*   step        = (const int*)  d_in[0];
    const float* token_embed = (const float*)d_in[2];
    const float* step_table  = (const float*)d_in[3];
    const float* w_ih_f = (const float*)d_in[4];
    const float* w_hh_f = (const float*)d_in[5];
    const float* b_ih_f = (const float*)d_in[6];
    const float* b_hh_f = (const float*)d_in[7];
    const float* w_ih_b = (const float*)d_in[8];
    const float* w_hh_b = (const float*)d_in[9];
    const float* b_ih_b = (const float*)d_in[10];
    const float* b_hh_b = (const float*)d_in[11];
    const float* film_w = (const float*)d_in[12];
    const float* film_b = (const float*)d_in[13];
    const float* dec_w  = (const float*)d_in[14];
    const float* dec_b  = (const float*)d_in[15];
    float* ws   = (float*)d_ws;
    float* outp = (float*)d_out;

    aag_precompute<<<TOTAL_PRE / 256, 256, 0, stream>>>(
        token_embed, step_table, w_ih_f, b_ih_f, w_ih_b, b_ih_b,
        film_w, film_b, ws);
    aag_decode<<<256, 512, 0, stream>>>(
        step, w_hh_f, b_hh_f, w_hh_b, b_hh_b, dec_w, dec_b, ws, outp);
}

// Round 4
// 1032.678 us; speedup vs baseline: 1.2775x; 1.1299x over previous
//
#include <hip/hip_runtime.h>
#include <cmath>

typedef float v2f __attribute__((ext_vector_type(2)));

#define GI_STRIDE (258*192)            // one gi table: 258 tokens x 192 gate-rows
#define FILM_OFF  (2*GI_STRIDE)        // 99072 floats
#define TOTAL_PRE (FILM_OFF + 256*256) // 164608 floats

#define B_TOT   1024
#define L_MAX   256
#define SOS_TOK 257
#define EOS_TOK 256

// pin a value in a register: volatile asm def cannot be rematerialized or
// sunk into the loop, so the weight stays resident instead of being
// re-fetched from L2 every step (round-2 failure mode, VGPR_Count=112).
// NOTE: "+v" tied constraint compiles for scalar float and v2f, but NOT for
// float4 (round-3 compile failure: "tied indirect register inputs").
#define KEEPF(x) asm volatile("" : "+v"(x))

// ---------------------------------------------------------------------------
// Prologue: gi tables (token_embed @ w_ih.T + b_ih, row-major 192/token) and
// FiLM table, stored as interleaved (gamma,beta) pairs per step.
// ---------------------------------------------------------------------------
__global__ __launch_bounds__(256) void aag_precompute(
    const float* __restrict__ token_embed,
    const float* __restrict__ step_table,
    const float* __restrict__ w_ih_f, const float* __restrict__ b_ih_f,
    const float* __restrict__ w_ih_b, const float* __restrict__ b_ih_b,
    const float* __restrict__ film_w, const float* __restrict__ film_b,
    float* __restrict__ ws)
{
    int idx = blockIdx.x * 256 + threadIdx.x;
    if (idx < FILM_OFF) {
        int m     = idx / GI_STRIDE;
        int rem   = idx - m * GI_STRIDE;
        int token = rem / 192;
        int r     = rem - token * 192;
        const float* wih = (m ? w_ih_b : w_ih_f) + r * 64;
        const float* te  = token_embed + token * 64;
        float acc = (m ? b_ih_b : b_ih_f)[r];
        #pragma unroll 8
        for (int k = 0; k < 64; ++k) acc += te[k] * wih[k];
        ws[idx] = acc;
    } else if (idx < TOTAL_PRE) {
        int q  = idx - FILM_OFF;
        int tt = q >> 8, j = q & 255;
        const float* st = step_table + tt * 16;
        const float* fw = film_w + j * 16;
        float acc = film_b[j];
        #pragma unroll
        for (int s = 0; s < 16; ++s) acc += st[s] * fw[s];
        // interleave: slot 2*(j&127) for gamma (j<128), +1 for beta (j>=128)
        int pos = (j < 128) ? (2 * j) : (2 * (j - 128) + 1);
        ws[FILM_OFF + tt * 256 + pos] = tanhf(acc);
    }
}

// ---------------------------------------------------------------------------
// Main persistent kernel: 256 blocks x 512 threads, 4 batch elements/block,
// 2-barrier ring:
//   P1: softmax(t-1) [replicated per wave pair, state in registers] + gate(t)
//   P2: decoder(t) + GRU matvec(t+1) merged (v_pk_fma_f32); film prefetch
// ---------------------------------------------------------------------------
__global__ __launch_bounds__(512)
__attribute__((amdgpu_waves_per_eu(2, 2)))
void aag_decode(
    const int* __restrict__ step_ptr,
    const float* __restrict__ w_hh_f, const float* __restrict__ b_hh_f,
    const float* __restrict__ w_hh_b, const float* __restrict__ b_hh_b,
    const float* __restrict__ dec_w, const float* __restrict__ dec_b,
    const float* __restrict__ ws,
    float* __restrict__ out)
{
    __shared__ __align__(16) float hbuf[2][4][64];   // h state (pre-FiLM)
    __shared__ __align__(16) float ghL[2][4][192];   // h @ w_hh.T + b_hh
    __shared__ __align__(16) float hsL[4][128];      // FiLMed concat state
    __shared__ __align__(16) float plL[4][256][2];   // decoder half-row sums
    __shared__ float eosP[4];                        // EOS-row logits (no bias)

    const int tid = threadIdx.x;
    const int wv  = tid >> 6;
    const int ln  = tid & 63;
    const int e   = wv >> 1;      // element this wave serves (softmax + gate)
    const int m   = wv & 1;       // GRU id this wave serves in gate phase

    // exponential-decay temperature, matching host double math
    float invT;
    {
        int step = step_ptr[0];
        if (step < 0) step = 0;
        double T = 0.2 + 2.3 * exp(-(0.6931471805599453 / 3000.0) * (double)step);
        if (T < 1e-6) T = 1e-6;
        invT = (float)(1.0 / T);
    }

    // ---- persistent weights in registers (pinned via KEEPF) ----
    const bool hasG = (ln < 48);
    const int  grow = wv * 48 + (hasG ? ln : 0);
    const int  gm   = (grow >= 192) ? 1 : 0;
    const int  gr   = grow - gm * 192;
    v2f  wg[32];
    float bG;
    {
        const float* whh = (gm ? w_hh_b : w_hh_f) + gr * 64;
        #pragma unroll
        for (int j = 0; j < 32; ++j) { wg[j] = ((const v2f*)whh)[j]; KEEPF(wg[j]); }
        bG = (gm ? b_hh_b : b_hh_f)[gr];
        KEEPF(bG);
    }
    // decoder: wave-uniform half split (threads 0-255 half 0, 256-511 half 1)
    const int dh  = tid >> 8;
    const int dro = tid & 255;
    v2f wd[32];
    {
        const float* dw = dec_w + dro * 128 + dh * 64;
        #pragma unroll
        for (int j = 0; j < 32; ++j) { wd[j] = ((const v2f*)dw)[j]; KEEPF(wd[j]); }
    }
    // EOS row chunks: threads 496..511 (wave 7, GRU-idle lanes), v2f pieces
    v2f ewa = {0,0}, ewb = {0,0}, ewc = {0,0}, ewd = {0,0};
    if (tid >= 496) {
        const v2f* p = (const v2f*)(dec_w + 256 * 128 + (tid - 496) * 8);
        ewa = p[0]; ewb = p[1]; ewc = p[2]; ewd = p[3];
        KEEPF(ewa); KEEPF(ewb); KEEPF(ewc); KEEPF(ewd);
    }
    // dec_b registers (used by softmax, every wave)
    float db0 = dec_b[ln], db1 = dec_b[64 + ln];
    float db2 = dec_b[128 + ln], db3 = dec_b[192 + ln];
    float db4 = (ln == 0) ? dec_b[256] : 0.f;
    KEEPF(db0); KEEPF(db1); KEEPF(db2); KEEPF(db3); KEEPF(db4);

    // ---- init ----
    ((float*)hbuf)[tid] = 0.f;                      // 512 floats = all of hbuf
    if (hasG) {                                     // gh(0) = bias (h(-1) = 0)
        ghL[gm][0][gr] = bG; ghL[gm][1][gr] = bG;
        ghL[gm][2][gr] = bG; ghL[gm][3][gr] = bG;
    }

    // per-wave register state (replicated on wave pairs, deterministic)
    bool s0m = false, s1m = false, s2m = false, s3m = false, s4m = false;
    bool done = false;

    // prefetch film(0) and gi(SOS)
    const float* filmT = ws + FILM_OFF;
    const float* giT   = ws + m * GI_STRIDE;
    float ga, be;
    {
        const float2 f = *(const float2*)&filmT[(m * 64 + ln) * 2];
        ga = f.x; be = f.y;
    }
    float gi_r, gi_z, gi_n;
    {
        const float* gp = giT + SOS_TOK * 192;
        gi_r = gp[ln]; gi_z = gp[64 + ln]; gi_n = gp[128 + ln];
    }

    const int b0 = blockIdx.x * 4;
    float* __restrict__ out_act = out;
    float* __restrict__ out_lp  = out + B_TOT * L_MAX;
    float* __restrict__ out_val = out + 2 * B_TOT * L_MAX;

    __syncthreads();   // ghL / hbuf init visible

    for (int t = 0; t <= L_MAX; ++t) {
        // ================= P1: softmax(t-1) + gate(t) =================
        if (t > 0) {
            const float2 q0 = *(const float2*)&plL[e][ln][0];
            const float2 q1 = *(const float2*)&plL[e][64 + ln][0];
            const float2 q2 = *(const float2*)&plL[e][128 + ln][0];
            const float2 q3 = *(const float2*)&plL[e][192 + ln][0];
            const float u0 = q0.x + q0.y + db0;
            const float u1 = q1.x + q1.y + db1;
            const float u2 = q2.x + q2.y + db2;
            const float u3 = q3.x + q3.y + db3;
            float mv = s0m ? -INFINITY : u0;
            int   mi = ln;
            { const float v = s1m ? -INFINITY : u1; if (v > mv) { mv = v; mi = 64 + ln; } }
            { const float v = s2m ? -INFINITY : u2; if (v > mv) { mv = v; mi = 128 + ln; } }
            { const float v = s3m ? -INFINITY : u3; if (v > mv) { mv = v; mi = 192 + ln; } }
            float u4 = 0.f;
            if (ln == 0) {
                u4 = eosP[e] + db4;
                const float v = s4m ? -INFINITY : u4;
                if (v > mv) { mv = v; mi = 256; }
            }
            // butterfly: max value, smallest index on ties (jnp.argmax semantics)
            #pragma unroll
            for (int off = 1; off < 64; off <<= 1) {
                const float ov = __shfl_xor(mv, off);
                const int   oi = __shfl_xor(mi, off);
                if (ov > mv || (ov == mv && oi < mi)) { mv = ov; mi = oi; }
            }
            const int a = __builtin_amdgcn_readfirstlane(mi);
            // issue gi loads for the next gate ASAP (L2 latency hides under exp sum)
            {
                const float* gp = giT + a * 192;
                gi_r = gp[ln]; gi_z = gp[64 + ln]; gi_n = gp[128 + ln];
            }
            // softmax denominator (feeds lp only -> fast exp is safe for actions)
            float S = 0.f;
            if (!s0m) S += __expf((u0 - mv) * invT);
            if (!s1m) S += __expf((u1 - mv) * invT);
            if (!s2m) S += __expf((u2 - mv) * invT);
            if (!s3m) S += __expf((u3 - mv) * invT);
            if (ln == 0 && !s4m) S += __expf((u4 - mv) * invT);
            #pragma unroll
            for (int off = 1; off < 64; off <<= 1) S += __shfl_xor(S, off);
            // state update (registers, replicated consistently on wave pairs)
            const bool wasdone = done;
            if (a == EOS_TOK) done = true;
            if ((a & 63) == ln) {
                if (a < 64) s0m = true; else if (a < 128) s1m = true;
                else if (a < 192) s2m = true; else if (a < 256) s3m = true;
                else s4m = true;
            }
            if (ln == 0 && m == 0) {
                const int b = b0 + e;
                out_act[b * L_MAX + (t - 1)] = (float)a;
                out_lp [b * L_MAX + (t - 1)] = wasdone ? 0.f : -__logf(S);
                out_val[b * L_MAX + (t - 1)] = wasdone ? 0.f : 1.f;
            }
        }
        if (t == L_MAX) break;

        // ---- gate(t): thread (m, e, ln) updates one hidden unit ----
        // (libm expf/tanhf: this feeds the h recurrence -> keep precise)
        {
            const float hr = ghL[m][e][ln];
            const float hz = ghL[m][e][64 + ln];
            const float hn = ghL[m][e][128 + ln];
            const float hp = hbuf[m][e][ln];
            const float r  = 1.f / (1.f + expf(-(gi_r + hr)));
            const float z  = 1.f / (1.f + expf(-(gi_z + hz)));
            const float n  = tanhf(gi_n + r * hn);
            const float h2 = (1.f - z) * n + z * hp;
            hbuf[m][e][ln] = h2;
            hsL[e][m * 64 + ln] = h2 * (1.f + ga) + be;
        }
        __syncthreads();   // B1: hbuf(t), hsL(t) ready

        // ================= P2: decoder(t) + GRU matvec(t+1) =================
        // film prefetch for t+1 (register, consumed next P1)
        {
            const int tn = (t + 1 < L_MAX) ? t + 1 : L_MAX - 1;
            const float2 f = *(const float2*)&filmT[tn * 256 + (m * 64 + ln) * 2];
            ga = f.x; be = f.y;
        }
        // decoder half-rows (broadcast hsL reads; packed v_pk_fma_f32)
        {
            v2f d0 = {0,0}, d1 = {0,0}, d2 = {0,0}, d3 = {0,0};
            const int hb = dh * 64;
            #pragma unroll
            for (int jj = 0; jj < 16; ++jj) {
                const float4 x0 = *(const float4*)&hsL[0][hb + 4 * jj];
                const float4 x1 = *(const float4*)&hsL[1][hb + 4 * jj];
                const float4 x2 = *(const float4*)&hsL[2][hb + 4 * jj];
                const float4 x3 = *(const float4*)&hsL[3][hb + 4 * jj];
                const v2f wlo = wd[2 * jj], whi = wd[2 * jj + 1];
                { v2f lo = {x0.x, x0.y}, hi = {x0.z, x0.w}; d0 = lo * wlo + d0; d0 = hi * whi + d0; }
                { v2f lo = {x1.x, x1.y}, hi = {x1.z, x1.w}; d1 = lo * wlo + d1; d1 = hi * whi + d1; }
                { v2f lo = {x2.x, x2.y}, hi = {x2.z, x2.w}; d2 = lo * wlo + d2; d2 = hi * whi + d2; }
                { v2f lo = {x3.x, x3.y}, hi = {x3.z, x3.w}; d3 = lo * wlo + d3; d3 = hi * whi + d3; }
            }
            plL[0][dro][dh] = d0.x + d0.y;
            plL[1][dro][dh] = d1.x + d1.y;
            plL[2][dro][dh] = d2.x + d2.y;
            plL[3][dro][dh] = d3.x + d3.y;
        }
        // GRU hidden matvec for step t+1 (broadcast hbuf reads; packed fma)
        if (hasG) {
            v2f a0 = {bG, 0.f}, a1 = {bG, 0.f}, a2 = {bG, 0.f}, a3 = {bG, 0.f};
            #pragma unroll
            for (int jj = 0; jj < 16; ++jj) {
                const float4 x0 = *(const float4*)&hbuf[gm][0][4 * jj];
                const float4 x1 = *(const float4*)&hbuf[gm][1][4 * jj];
                const float4 x2 = *(const float4*)&hbuf[gm][2][4 * jj];
                const float4 x3 = *(const float4*)&hbuf[gm][3][4 * jj];
                const v2f wlo = wg[2 * jj], whi = wg[2 * jj + 1];
                { v2f lo = {x0.x, x0.y}, hi = {x0.z, x0.w}; a0 = lo * wlo + a0; a0 = hi * whi + a0; }
                { v2f lo = {x1.x, x1.y}, hi = {x1.z, x1.w}; a1 = lo * wlo + a1; a1 = hi * whi + a1; }
                { v2f lo = {x2.x, x2.y}, hi = {x2.z, x2.w}; a2 = lo * wlo + a2; a2 = hi * whi + a2; }
                { v2f lo = {x3.x, x3.y}, hi = {x3.z, x3.w}; a3 = lo * wlo + a3; a3 = hi * whi + a3; }
            }
            ghL[gm][0][gr] = a0.x + a0.y; ghL[gm][1][gr] = a1.x + a1.y;
            ghL[gm][2][gr] = a2.x + a2.y; ghL[gm][3][gr] = a3.x + a3.y;
        }
        // EOS row partials: threads 496..511, 8-wide chunks + 16-lane butterfly
        if (tid >= 496) {
            const int c = tid - 496;
            float t0, t1, t2, t3;
            {
                const float4 p0 = *(const float4*)&hsL[0][8 * c];
                const float4 p1 = *(const float4*)&hsL[0][8 * c + 4];
                t0 = p0.x*ewa.x + p0.y*ewa.y + p0.z*ewb.x + p0.w*ewb.y
                   + p1.x*ewc.x + p1.y*ewc.y + p1.z*ewd.x + p1.w*ewd.y;
            }
            {
                const float4 p0 = *(const float4*)&hsL[1][8 * c];
                const float4 p1 = *(const float4*)&hsL[1][8 * c + 4];
                t1 = p0.x*ewa.x + p0.y*ewa.y + p0.z*ewb.x + p0.w*ewb.y
                   + p1.x*ewc.x + p1.y*ewc.y + p1.z*ewd.x + p1.w*ewd.y;
            }
            {
                const float4 p0 = *(const float4*)&hsL[2][8 * c];
                const float4 p1 = *(const float4*)&hsL[2][8 * c + 4];
                t2 = p0.x*ewa.x + p0.y*ewa.y + p0.z*ewb.x + p0.w*ewb.y
                   + p1.x*ewc.x + p1.y*ewc.y + p1.z*ewd.x + p1.w*ewd.y;
            }
            {
                const float4 p0 = *(const float4*)&hsL[3][8 * c];
                const float4 p1 = *(const float4*)&hsL[3][8 * c + 4];
                t3 = p0.x*ewa.x + p0.y*ewa.y + p0.z*ewb.x + p0.w*ewb.y
                   + p1.x*ewc.x + p1.y*ewc.y + p1.z*ewd.x + p1.w*ewd.y;
            }
            #pragma unroll
            for (int off = 1; off < 16; off <<= 1) {
                t0 += __shfl_xor(t0, off); t1 += __shfl_xor(t1, off);
                t2 += __shfl_xor(t2, off); t3 += __shfl_xor(t3, off);
            }
            if (c == 0) { eosP[0] = t0; eosP[1] = t1; eosP[2] = t2; eosP[3] = t3; }
        }
        __syncthreads();   // B2: plL(t), eosP(t), ghL(t+1) ready
    }
}

extern "C" void kernel_launch(void* const* d_in, const int* in_sizes, int n_in,
                              void* d_out, int out_size, void* d_ws, size_t ws_size,
                              hipStream_t stream)
{
    const int*   step        = (const int*)  d_in[0];
    const float* token_embed = (const float*)d_in[2];
    const float* step_table  = (const float*)d_in[3];
    const float* w_ih_f = (const float*)d_in[4];
    const float* w_hh_f = (const float*)d_in[5];
    const float* b_ih_f = (const float*)d_in[6];
    const float* b_hh_f = (const float*)d_in[7];
    const float* w_ih_b = (const float*)d_in[8];
    const float* w_hh_b = (const float*)d_in[9];
    const float* b_ih_b = (const float*)d_in[10];
    const float* b_hh_b = (const float*)d_in[11];
    const float* film_w = (const float*)d_in[12];
    const float* film_b = (const float*)d_in[13];
    const float* dec_w  = (const float*)d_in[14];
    const float* dec_b  = (const float*)d_in[15];
    float* ws   = (float*)d_ws;
    float* outp = (float*)d_out;

    aag_precompute<<<TOTAL_PRE / 256, 256, 0, stream>>>(
        token_embed, step_table, w_ih_f, b_ih_f, w_ih_b, b_ih_b,
        film_w, film_b, ws);
    aag_decode<<<256, 512, 0, stream>>>(
        step, w_hh_f, b_hh_f, w_hh_b, b_hh_b, dec_w, dec_b, ws, outp);
}

// Round 5
// 825.294 us; speedup vs baseline: 1.5985x; 1.2513x over previous
//
#include <hip/hip_runtime.h>
#include <cmath>

typedef float v2f __attribute__((ext_vector_type(2)));

#define GI_STRIDE (258*192)            // one gi table: 258 tokens x 192 gate-rows
#define FILM_OFF  (2*GI_STRIDE)        // 99072 floats
#define TOTAL_PRE (FILM_OFF + 256*256) // 164608 floats

#define B_TOT   1024
#define L_MAX   256
#define SOS_TOK 257
#define EOS_TOK 256

// pin a value in a register (scalar/v2f only; float4 fails to compile)
#define KEEPF(x) asm volatile("" : "+v"(x))

// ---------------------------------------------------------------------------
// Prologue: gi tables (token_embed @ w_ih.T + b_ih) and FiLM table stored as
// interleaved (gamma,beta) pairs per step.
// ---------------------------------------------------------------------------
__global__ __launch_bounds__(256) void aag_precompute(
    const float* __restrict__ token_embed,
    const float* __restrict__ step_table,
    const float* __restrict__ w_ih_f, const float* __restrict__ b_ih_f,
    const float* __restrict__ w_ih_b, const float* __restrict__ b_ih_b,
    const float* __restrict__ film_w, const float* __restrict__ film_b,
    float* __restrict__ ws)
{
    int idx = blockIdx.x * 256 + threadIdx.x;
    if (idx < FILM_OFF) {
        int m     = idx / GI_STRIDE;
        int rem   = idx - m * GI_STRIDE;
        int token = rem / 192;
        int r     = rem - token * 192;
        const float* wih = (m ? w_ih_b : w_ih_f) + r * 64;
        const float* te  = token_embed + token * 64;
        float acc = (m ? b_ih_b : b_ih_f)[r];
        #pragma unroll 8
        for (int k = 0; k < 64; ++k) acc += te[k] * wih[k];
        ws[idx] = acc;
    } else if (idx < TOTAL_PRE) {
        int q  = idx - FILM_OFF;
        int tt = q >> 8, j = q & 255;
        const float* st = step_table + tt * 16;
        const float* fw = film_w + j * 16;
        float acc = film_b[j];
        #pragma unroll
        for (int s = 0; s < 16; ++s) acc += st[s] * fw[s];
        int pos = (j < 128) ? (2 * j) : (2 * (j - 128) + 1);
        ws[FILM_OFF + tt * 256 + pos] = tanhf(acc);
    }
}

// ---------------------------------------------------------------------------
// Main persistent kernel: 256 blocks x 512 threads, 4 elems/block.
// Role-split, operand-reuse-2 (each thread: 2 output rows per loaded operand):
//   threads   0..255 : decoder, rows (2dq,2dq+1) x half dh (wave-uniform)
//   threads 256..271 : EOS row 256, 8-float chunks
//   threads 320..511 : GRU, rows (2gp,2gp+1) of matrix gm
// All threads: gate unit (m,e,ln); all waves: replicated softmax for e=wv>>1.
// ---------------------------------------------------------------------------
__global__ __launch_bounds__(512)
__attribute__((amdgpu_waves_per_eu(2, 2)))
void aag_decode(
    const int* __restrict__ step_ptr,
    const float* __restrict__ w_hh_f, const float* __restrict__ b_hh_f,
    const float* __restrict__ w_hh_b, const float* __restrict__ b_hh_b,
    const float* __restrict__ dec_w, const float* __restrict__ dec_b,
    const float* __restrict__ ws,
    float* __restrict__ out)
{
    __shared__ __align__(16) float hbuf[2][4][64];   // h state (pre-FiLM)
    __shared__ __align__(16) float ghL[2][4][192];   // h @ w_hh.T + b_hh
    __shared__ __align__(16) float hsL[4][128];      // FiLMed concat state
    __shared__ __align__(16) float plL[2][4][264];   // [half][e][row] partials

    const int tid = threadIdx.x;
    const int wv  = tid >> 6;
    const int ln  = tid & 63;
    const int e   = wv >> 1;      // softmax element for this wave
    const int m   = wv & 1;       // gate-phase GRU id for this wave

    // exponential-decay temperature, matching host double math
    float invT;
    {
        int step = step_ptr[0];
        if (step < 0) step = 0;
        double T = 0.2 + 2.3 * exp(-(0.6931471805599453 / 3000.0) * (double)step);
        if (T < 1e-6) T = 1e-6;
        invT = (float)(1.0 / T);
    }

    // ---- roles ----
    const bool isDec = (tid < 256);
    const bool isEos = (tid >= 256 && tid < 272);
    const bool isGru = (tid >= 320);
    const int  dh    = tid >> 7;          // decoder half (waves 0-1: 0, waves 2-3: 1)
    const int  dq    = tid & 127;         // decoder row-pair index
    const int  gj    = tid - 320;
    const int  gm    = (gj >= 96) ? 1 : 0;
    const int  gp    = gj - 96 * gm;      // gru row-pair index
    const int  ec    = tid - 256;         // eos chunk index

    // ---- persistent weights: one shared array (roles are wave-exclusive) ----
    v2f wreg[64];
    #pragma unroll
    for (int j = 0; j < 64; ++j) wreg[j] = (v2f){0.f, 0.f};
    v2f bias2 = {0.f, 0.f};
    if (isDec) {
        const float* dw = dec_w + (2 * dq) * 128 + dh * 64;
        #pragma unroll
        for (int k = 0; k < 64; ++k) wreg[k] = (v2f){dw[k], dw[128 + k]};
    } else if (isGru) {
        const float* whh = (gm ? w_hh_b : w_hh_f) + (2 * gp) * 64;
        #pragma unroll
        for (int k = 0; k < 64; ++k) wreg[k] = (v2f){whh[k], whh[64 + k]};
        const float* bhh = (gm ? b_hh_b : b_hh_f) + 2 * gp;
        bias2 = (v2f){bhh[0], bhh[1]};
    } else if (isEos) {
        const float* p = dec_w + 256 * 128 + ec * 8;
        #pragma unroll
        for (int k = 0; k < 4; ++k) wreg[k] = (v2f){p[2 * k], p[2 * k + 1]};
    }
    #pragma unroll
    for (int j = 0; j < 64; ++j) KEEPF(wreg[j]);
    KEEPF(bias2);

    // dec_b registers (softmax, every wave)
    float db0 = dec_b[ln], db1 = dec_b[64 + ln];
    float db2 = dec_b[128 + ln], db3 = dec_b[192 + ln];
    float db4 = (ln == 0) ? dec_b[256] : 0.f;
    KEEPF(db0); KEEPF(db1); KEEPF(db2); KEEPF(db3); KEEPF(db4);

    // ---- init ----
    ((float*)hbuf)[tid] = 0.f;                      // 512 floats = all of hbuf
    if (isGru) {                                    // gh(0) = bias (h(-1)=0)
        #pragma unroll
        for (int e2 = 0; e2 < 4; ++e2)
            *(v2f*)&ghL[gm][e2][2 * gp] = bias2;
    }

    // per-wave register state (replicated per wave, deterministic)
    bool s0m = false, s1m = false, s2m = false, s3m = false, s4m = false;
    bool done = false;

    // prefetch film(0) and gi(SOS)
    const float* filmT = ws + FILM_OFF;
    const float* giT   = ws + m * GI_STRIDE;
    float ga, be;
    {
        const float2 f = *(const float2*)&filmT[(m * 64 + ln) * 2];
        ga = f.x; be = f.y;
    }
    float gi_r, gi_z, gi_n;
    {
        const float* gp2 = giT + SOS_TOK * 192;
        gi_r = gp2[ln]; gi_z = gp2[64 + ln]; gi_n = gp2[128 + ln];
    }

    const int b0 = blockIdx.x * 4;
    float* __restrict__ out_act = out;
    float* __restrict__ out_lp  = out + B_TOT * L_MAX;
    float* __restrict__ out_val = out + 2 * B_TOT * L_MAX;

    __syncthreads();   // ghL / hbuf init visible

    for (int t = 0; t <= L_MAX; ++t) {
        // ================= P1: softmax(t-1) + gate(t) =================
        if (t > 0) {
            const float u0 = plL[0][e][ln]       + plL[1][e][ln]       + db0;
            const float u1 = plL[0][e][64 + ln]  + plL[1][e][64 + ln]  + db1;
            const float u2 = plL[0][e][128 + ln] + plL[1][e][128 + ln] + db2;
            const float u3 = plL[0][e][192 + ln] + plL[1][e][192 + ln] + db3;
            float mv = s0m ? -INFINITY : u0;
            int   mi = ln;
            { const float v = s1m ? -INFINITY : u1; if (v > mv) { mv = v; mi = 64 + ln; } }
            { const float v = s2m ? -INFINITY : u2; if (v > mv) { mv = v; mi = 128 + ln; } }
            { const float v = s3m ? -INFINITY : u3; if (v > mv) { mv = v; mi = 192 + ln; } }
            float u4 = 0.f;
            if (ln == 0) {
                u4 = plL[0][e][256] + db4;
                const float v = s4m ? -INFINITY : u4;
                if (v > mv) { mv = v; mi = 256; }
            }
            // butterfly: max value, smallest index on ties (jnp.argmax semantics)
            #pragma unroll
            for (int off = 1; off < 64; off <<= 1) {
                const float ov = __shfl_xor(mv, off);
                const int   oi = __shfl_xor(mi, off);
                if (ov > mv || (ov == mv && oi < mi)) { mv = ov; mi = oi; }
            }
            const int a = __builtin_amdgcn_readfirstlane(mi);
            // gi loads for gate(t) ASAP (L2 latency hides under exp sum)
            {
                const float* gp2 = giT + a * 192;
                gi_r = gp2[ln]; gi_z = gp2[64 + ln]; gi_n = gp2[128 + ln];
            }
            // softmax denominator (feeds lp only)
            float S = 0.f;
            if (!s0m) S += __expf((u0 - mv) * invT);
            if (!s1m) S += __expf((u1 - mv) * invT);
            if (!s2m) S += __expf((u2 - mv) * invT);
            if (!s3m) S += __expf((u3 - mv) * invT);
            if (ln == 0 && !s4m) S += __expf((u4 - mv) * invT);
            #pragma unroll
            for (int off = 1; off < 64; off <<= 1) S += __shfl_xor(S, off);
            // state update (registers, replicated consistently per wave)
            const bool wasdone = done;
            if (a == EOS_TOK) done = true;
            if ((a & 63) == ln) {
                if (a < 64) s0m = true; else if (a < 128) s1m = true;
                else if (a < 192) s2m = true; else if (a < 256) s3m = true;
                else s4m = true;
            }
            if (ln == 0 && m == 0) {
                const int b = b0 + e;
                out_act[b * L_MAX + (t - 1)] = (float)a;
                out_lp [b * L_MAX + (t - 1)] = wasdone ? 0.f : -__logf(S);
                out_val[b * L_MAX + (t - 1)] = wasdone ? 0.f : 1.f;
            }
        }
        if (t == L_MAX) break;

        // ---- gate(t): thread (m, e, ln) updates one hidden unit ----
        {
            const float hr = ghL[m][e][ln];
            const float hz = ghL[m][e][64 + ln];
            const float hn = ghL[m][e][128 + ln];
            const float hp = hbuf[m][e][ln];
            const float r  = 1.f / (1.f + expf(-(gi_r + hr)));
            const float z  = 1.f / (1.f + expf(-(gi_z + hz)));
            const float n  = tanhf(gi_n + r * hn);
            const float h2 = (1.f - z) * n + z * hp;
            hbuf[m][e][ln] = h2;
            hsL[e][m * 64 + ln] = h2 * (1.f + ga) + be;
        }
        __syncthreads();   // B1: hbuf(t), hsL(t) ready

        // ================= P2: matvecs (reuse-2, pair-packed rows) =========
        // film prefetch for t+1
        {
            const int tn = (t + 1 < L_MAX) ? t + 1 : L_MAX - 1;
            const float2 f = *(const float2*)&filmT[tn * 256 + (m * 64 + ln) * 2];
            ga = f.x; be = f.y;
        }
        if (isDec) {
            v2f a0 = {0,0}, a1 = {0,0}, a2 = {0,0}, a3 = {0,0};
            const int hb = dh * 64;
            #pragma unroll
            for (int jj = 0; jj < 16; ++jj) {
                const float4 x0 = *(const float4*)&hsL[0][hb + 4 * jj];
                const float4 x1 = *(const float4*)&hsL[1][hb + 4 * jj];
                const float4 x2 = *(const float4*)&hsL[2][hb + 4 * jj];
                const float4 x3 = *(const float4*)&hsL[3][hb + 4 * jj];
                const v2f w0 = wreg[4*jj], w1 = wreg[4*jj+1], w2 = wreg[4*jj+2], w3 = wreg[4*jj+3];
                a0 = w0*(v2f){x0.x,x0.x} + a0; a0 = w1*(v2f){x0.y,x0.y} + a0;
                a0 = w2*(v2f){x0.z,x0.z} + a0; a0 = w3*(v2f){x0.w,x0.w} + a0;
                a1 = w0*(v2f){x1.x,x1.x} + a1; a1 = w1*(v2f){x1.y,x1.y} + a1;
                a1 = w2*(v2f){x1.z,x1.z} + a1; a1 = w3*(v2f){x1.w,x1.w} + a1;
                a2 = w0*(v2f){x2.x,x2.x} + a2; a2 = w1*(v2f){x2.y,x2.y} + a2;
                a2 = w2*(v2f){x2.z,x2.z} + a2; a2 = w3*(v2f){x2.w,x2.w} + a2;
                a3 = w0*(v2f){x3.x,x3.x} + a3; a3 = w1*(v2f){x3.y,x3.y} + a3;
                a3 = w2*(v2f){x3.z,x3.z} + a3; a3 = w3*(v2f){x3.w,x3.w} + a3;
            }
            *(v2f*)&plL[dh][0][2 * dq] = a0;
            *(v2f*)&plL[dh][1][2 * dq] = a1;
            *(v2f*)&plL[dh][2][2 * dq] = a2;
            *(v2f*)&plL[dh][3][2 * dq] = a3;
        } else if (isGru) {
            v2f a0 = bias2, a1 = bias2, a2 = bias2, a3 = bias2;
            #pragma unroll
            for (int jj = 0; jj < 16; ++jj) {
                const float4 x0 = *(const float4*)&hbuf[gm][0][4 * jj];
                const float4 x1 = *(const float4*)&hbuf[gm][1][4 * jj];
                const float4 x2 = *(const float4*)&hbuf[gm][2][4 * jj];
                const float4 x3 = *(const float4*)&hbuf[gm][3][4 * jj];
                const v2f w0 = wreg[4*jj], w1 = wreg[4*jj+1], w2 = wreg[4*jj+2], w3 = wreg[4*jj+3];
                a0 = w0*(v2f){x0.x,x0.x} + a0; a0 = w1*(v2f){x0.y,x0.y} + a0;
                a0 = w2*(v2f){x0.z,x0.z} + a0; a0 = w3*(v2f){x0.w,x0.w} + a0;
                a1 = w0*(v2f){x1.x,x1.x} + a1; a1 = w1*(v2f){x1.y,x1.y} + a1;
                a1 = w2*(v2f){x1.z,x1.z} + a1; a1 = w3*(v2f){x1.w,x1.w} + a1;
                a2 = w0*(v2f){x2.x,x2.x} + a2; a2 = w1*(v2f){x2.y,x2.y} + a2;
                a2 = w2*(v2f){x2.z,x2.z} + a2; a2 = w3*(v2f){x2.w,x2.w} + a2;
                a3 = w0*(v2f){x3.x,x3.x} + a3; a3 = w1*(v2f){x3.y,x3.y} + a3;
                a3 = w2*(v2f){x3.z,x3.z} + a3; a3 = w3*(v2f){x3.w,x3.w} + a3;
            }
            *(v2f*)&ghL[gm][0][2 * gp] = a0;
            *(v2f*)&ghL[gm][1][2 * gp] = a1;
            *(v2f*)&ghL[gm][2][2 * gp] = a2;
            *(v2f*)&ghL[gm][3][2 * gp] = a3;
        } else if (isEos) {
            float t0, t1, t2, t3;
            {
                const float4 p0 = *(const float4*)&hsL[0][8 * ec];
                const float4 p1 = *(const float4*)&hsL[0][8 * ec + 4];
                t0 = p0.x*wreg[0].x + p0.y*wreg[0].y + p0.z*wreg[1].x + p0.w*wreg[1].y
                   + p1.x*wreg[2].x + p1.y*wreg[2].y + p1.z*wreg[3].x + p1.w*wreg[3].y;
            }
            {
                const float4 p0 = *(const float4*)&hsL[1][8 * ec];
                const float4 p1 = *(const float4*)&hsL[1][8 * ec + 4];
                t1 = p0.x*wreg[0].x + p0.y*wreg[0].y + p0.z*wreg[1].x + p0.w*wreg[1].y
                   + p1.x*wreg[2].x + p1.y*wreg[2].y + p1.z*wreg[3].x + p1.w*wreg[3].y;
            }
            {
                const float4 p0 = *(const float4*)&hsL[2][8 * ec];
                const float4 p1 = *(const float4*)&hsL[2][8 * ec + 4];
                t2 = p0.x*wreg[0].x + p0.y*wreg[0].y + p0.z*wreg[1].x + p0.w*wreg[1].y
                   + p1.x*wreg[2].x + p1.y*wreg[2].y + p1.z*wreg[3].x + p1.w*wreg[3].y;
            }
            {
                const float4 p0 = *(const float4*)&hsL[3][8 * ec];
                const float4 p1 = *(const float4*)&hsL[3][8 * ec + 4];
                t3 = p0.x*wreg[0].x + p0.y*wreg[0].y + p0.z*wreg[1].x + p0.w*wreg[1].y
                   + p1.x*wreg[2].x + p1.y*wreg[2].y + p1.z*wreg[3].x + p1.w*wreg[3].y;
            }
            #pragma unroll
            for (int off = 1; off < 16; off <<= 1) {
                t0 += __shfl_xor(t0, off); t1 += __shfl_xor(t1, off);
                t2 += __shfl_xor(t2, off); t3 += __shfl_xor(t3, off);
            }
            if (ec == 0) {
                plL[0][0][256] = t0; plL[0][1][256] = t1;
                plL[0][2][256] = t2; plL[0][3][256] = t3;
                plL[1][0][256] = 0.f; plL[1][1][256] = 0.f;
                plL[1][2][256] = 0.f; plL[1][3][256] = 0.f;
            }
        }
        __syncthreads();   // B2: plL(t), ghL(t+1) ready
    }
}

extern "C" void kernel_launch(void* const* d_in, const int* in_sizes, int n_in,
                              void* d_out, int out_size, void* d_ws, size_t ws_size,
                              hipStream_t stream)
{
    const int*   step        = (const int*)  d_in[0];
    const float* token_embed = (const float*)d_in[2];
    const float* step_table  = (const float*)d_in[3];
    const float* w_ih_f = (const float*)d_in[4];
    const float* w_hh_f = (const float*)d_in[5];
    const float* b_ih_f = (const float*)d_in[6];
    const float* b_hh_f = (const float*)d_in[7];
    const float* w_ih_b = (const float*)d_in[8];
    const float* w_hh_b = (const float*)d_in[9];
    const float* b_ih_b = (const float*)d_in[10];
    const float* b_hh_b = (const float*)d_in[11];
    const float* film_w = (const float*)d_in[12];
    const float* film_b = (const float*)d_in[13];
    const float* dec_w  = (const float*)d_in[14];
    const float* dec_b  = (const float*)d_in[15];
    float* ws   = (float*)d_ws;
    float* outp = (float*)d_out;

    aag_precompute<<<TOTAL_PRE / 256, 256, 0, stream>>>(
        token_embed, step_table, w_ih_f, b_ih_f, w_ih_b, b_ih_b,
        film_w, film_b, ws);
    aag_decode<<<256, 512, 0, stream>>>(
        step, w_hh_f, b_hh_f, w_hh_b, b_hh_b, dec_w, dec_b, ws, outp);
}

// Round 6
// 694.037 us; speedup vs baseline: 1.9008x; 1.1891x over previous
//
#include <hip/hip_runtime.h>
#include <cmath>

typedef float v2f __attribute__((ext_vector_type(2)));

#define GI_STRIDE (258*192)            // one gi table: 258 tokens x 192 gate-rows
#define FILM_OFF  (2*GI_STRIDE)        // 99072 floats
#define TOTAL_PRE (FILM_OFF + 256*256) // 164608 floats

#define B_TOT   1024
#define L_MAX   256
#define SOS_TOK 257
#define EOS_TOK 256

// pin a value in a register (scalar/v2f only; float4 fails to compile)
#define KEEPF(x) asm volatile("" : "+v"(x))

// v_pk_fma_f32 with op_sel broadcast of one 32-bit half of x (a v2f pair):
//   PK_LO: acc.{lo,hi} += w.{lo,hi} * x.lo
//   PK_HI: acc.{lo,hi} += w.{lo,hi} * x.hi
#define PK_LO(acc, w, x) asm("v_pk_fma_f32 %0, %1, %2, %0 op_sel:[0,0,0] op_sel_hi:[1,0,1]" : "+v"(acc) : "v"(w), "v"(x))
#define PK_HI(acc, w, x) asm("v_pk_fma_f32 %0, %1, %2, %0 op_sel:[0,1,0] op_sel_hi:[1,1,1]" : "+v"(acc) : "v"(w), "v"(x))

// DPP helpers (VALU pipe, ~4cyc/stage vs ~50cyc ds_permute shuffles)
#define DPPI(old, src, ctrl, rmask) __builtin_amdgcn_update_dpp(old, src, ctrl, rmask, 0xF, false)

// argmax (value, smallest index on ties) combine stage
#define AMAX_STAGE(ctrl, rmask) do { \
    const int   _vi = __builtin_bit_cast(int, mv); \
    const float _ov = __builtin_bit_cast(float, DPPI(_vi, _vi, ctrl, rmask)); \
    const int   _oi = DPPI(mi, mi, ctrl, rmask); \
    if (_ov > mv || (_ov == mv && _oi < mi)) { mv = _ov; mi = _oi; } \
} while (0)

// sum combine stage (invalid/unselected lanes contribute 0)
#define SUM_STAGE(s, ctrl, rmask) do { \
    (s) += __builtin_bit_cast(float, DPPI(0, __builtin_bit_cast(int, (s)), ctrl, rmask)); \
} while (0)

// full 64-lane reduce: row prefix (shr 1,2,4,8) then cross-row bcast; lane 63
#define AMAX64() do { \
    AMAX_STAGE(0x111, 0xF); AMAX_STAGE(0x112, 0xF); \
    AMAX_STAGE(0x114, 0xF); AMAX_STAGE(0x118, 0xF); \
    AMAX_STAGE(0x142, 0xA); AMAX_STAGE(0x143, 0xC); \
} while (0)
#define SUM64(s) do { \
    SUM_STAGE(s, 0x111, 0xF); SUM_STAGE(s, 0x112, 0xF); \
    SUM_STAGE(s, 0x114, 0xF); SUM_STAGE(s, 0x118, 0xF); \
    SUM_STAGE(s, 0x142, 0xA); SUM_STAGE(s, 0x143, 0xC); \
} while (0)
// 16-lane (row) sum: total lands in lane 15 of each row
#define SUM16(s) do { \
    SUM_STAGE(s, 0x111, 0xF); SUM_STAGE(s, 0x112, 0xF); \
    SUM_STAGE(s, 0x114, 0xF); SUM_STAGE(s, 0x118, 0xF); \
} while (0)

// ---------------------------------------------------------------------------
// Prologue: gi tables (token_embed @ w_ih.T + b_ih) and FiLM table stored as
// interleaved (gamma,beta) pairs per step.
// ---------------------------------------------------------------------------
__global__ __launch_bounds__(256) void aag_precompute(
    const float* __restrict__ token_embed,
    const float* __restrict__ step_table,
    const float* __restrict__ w_ih_f, const float* __restrict__ b_ih_f,
    const float* __restrict__ w_ih_b, const float* __restrict__ b_ih_b,
    const float* __restrict__ film_w, const float* __restrict__ film_b,
    float* __restrict__ ws)
{
    int idx = blockIdx.x * 256 + threadIdx.x;
    if (idx < FILM_OFF) {
        int m     = idx / GI_STRIDE;
        int rem   = idx - m * GI_STRIDE;
        int token = rem / 192;
        int r     = rem - token * 192;
        const float* wih = (m ? w_ih_b : w_ih_f) + r * 64;
        const float* te  = token_embed + token * 64;
        float acc = (m ? b_ih_b : b_ih_f)[r];
        #pragma unroll 8
        for (int k = 0; k < 64; ++k) acc += te[k] * wih[k];
        ws[idx] = acc;
    } else if (idx < TOTAL_PRE) {
        int q  = idx - FILM_OFF;
        int tt = q >> 8, j = q & 255;
        const float* st = step_table + tt * 16;
        const float* fw = film_w + j * 16;
        float acc = film_b[j];
        #pragma unroll
        for (int s = 0; s < 16; ++s) acc += st[s] * fw[s];
        int pos = (j < 128) ? (2 * j) : (2 * (j - 128) + 1);
        ws[FILM_OFF + tt * 256 + pos] = tanhf(acc);
    }
}

// ---------------------------------------------------------------------------
// Main persistent kernel: 256 blocks x 512 threads, 4 elems/block.
// Role-split, reuse-2 matvecs (asm pk_fma), DPP softmax reductions.
// ---------------------------------------------------------------------------
__global__ __launch_bounds__(512)
__attribute__((amdgpu_waves_per_eu(2, 2)))
void aag_decode(
    const int* __restrict__ step_ptr,
    const float* __restrict__ w_hh_f, const float* __restrict__ b_hh_f,
    const float* __restrict__ w_hh_b, const float* __restrict__ b_hh_b,
    const float* __restrict__ dec_w, const float* __restrict__ dec_b,
    const float* __restrict__ ws,
    float* __restrict__ out)
{
    __shared__ __align__(16) float hbuf[2][4][64];   // h state (pre-FiLM)
    __shared__ __align__(16) float ghL[2][4][192];   // h @ w_hh.T + b_hh
    __shared__ __align__(16) float hsL[4][128];      // FiLMed concat state
    __shared__ __align__(16) float plL[2][4][264];   // [half][e][row] partials

    const int tid = threadIdx.x;
    const int wv  = tid >> 6;
    const int ln  = tid & 63;
    const int e   = wv >> 1;      // softmax element for this wave
    const int m   = wv & 1;       // gate-phase GRU id for this wave

    // exponential-decay temperature, matching host double math
    float invT;
    {
        int step = step_ptr[0];
        if (step < 0) step = 0;
        double T = 0.2 + 2.3 * exp(-(0.6931471805599453 / 3000.0) * (double)step);
        if (T < 1e-6) T = 1e-6;
        invT = (float)(1.0 / T);
    }

    // ---- roles ----
    const bool isDec = (tid < 256);
    const bool isEos = (tid >= 256 && tid < 272);
    const bool isGru = (tid >= 320);
    const int  dh    = tid >> 7;          // decoder half (waves 0-1: 0, waves 2-3: 1)
    const int  dq    = tid & 127;         // decoder row-pair index
    const int  gj    = tid - 320;
    const int  gm    = (gj >= 96) ? 1 : 0;
    const int  gp    = gj - 96 * gm;      // gru row-pair index
    const int  ec    = tid - 256;         // eos chunk index

    // ---- persistent weights: one shared array (roles are wave-exclusive) ----
    v2f wreg[64];
    #pragma unroll
    for (int j = 0; j < 64; ++j) wreg[j] = (v2f){0.f, 0.f};
    v2f bias2 = {0.f, 0.f};
    if (isDec) {
        const float* dw = dec_w + (2 * dq) * 128 + dh * 64;
        #pragma unroll
        for (int k = 0; k < 64; ++k) wreg[k] = (v2f){dw[k], dw[128 + k]};
    } else if (isGru) {
        const float* whh = (gm ? w_hh_b : w_hh_f) + (2 * gp) * 64;
        #pragma unroll
        for (int k = 0; k < 64; ++k) wreg[k] = (v2f){whh[k], whh[64 + k]};
        const float* bhh = (gm ? b_hh_b : b_hh_f) + 2 * gp;
        bias2 = (v2f){bhh[0], bhh[1]};
    } else if (isEos) {
        const float* p = dec_w + 256 * 128 + ec * 8;
        #pragma unroll
        for (int k = 0; k < 4; ++k) wreg[k] = (v2f){p[2 * k], p[2 * k + 1]};
    }
    #pragma unroll
    for (int j = 0; j < 64; ++j) KEEPF(wreg[j]);
    KEEPF(bias2);

    // dec_b registers (softmax, every wave)
    float db0 = dec_b[ln], db1 = dec_b[64 + ln];
    float db2 = dec_b[128 + ln], db3 = dec_b[192 + ln];
    float db4 = (ln == 0) ? dec_b[256] : 0.f;
    KEEPF(db0); KEEPF(db1); KEEPF(db2); KEEPF(db3); KEEPF(db4);

    // ---- init ----
    ((float*)hbuf)[tid] = 0.f;                      // 512 floats = all of hbuf
    if (isGru) {                                    // gh(0) = bias (h(-1)=0)
        #pragma unroll
        for (int e2 = 0; e2 < 4; ++e2)
            *(v2f*)&ghL[gm][e2][2 * gp] = bias2;
    }

    // per-wave register state (replicated per wave, deterministic)
    bool s0m = false, s1m = false, s2m = false, s3m = false, s4m = false;
    bool done = false;

    // prefetch film(0) and gi(SOS)
    const float* filmT = ws + FILM_OFF;
    const float* giT   = ws + m * GI_STRIDE;
    float ga, be;
    {
        const float2 f = *(const float2*)&filmT[(m * 64 + ln) * 2];
        ga = f.x; be = f.y;
    }
    float gi_r, gi_z, gi_n;
    {
        const float* gp2 = giT + SOS_TOK * 192;
        gi_r = gp2[ln]; gi_z = gp2[64 + ln]; gi_n = gp2[128 + ln];
    }

    const int b0 = blockIdx.x * 4;
    float* __restrict__ out_act = out;
    float* __restrict__ out_lp  = out + B_TOT * L_MAX;
    float* __restrict__ out_val = out + 2 * B_TOT * L_MAX;

    __syncthreads();   // ghL / hbuf init visible

    for (int t = 0; t <= L_MAX; ++t) {
        // ================= P1: softmax(t-1) + gate(t) =================
        if (t > 0) {
            const float u0 = plL[0][e][ln]       + plL[1][e][ln]       + db0;
            const float u1 = plL[0][e][64 + ln]  + plL[1][e][64 + ln]  + db1;
            const float u2 = plL[0][e][128 + ln] + plL[1][e][128 + ln] + db2;
            const float u3 = plL[0][e][192 + ln] + plL[1][e][192 + ln] + db3;
            float mv = s0m ? -INFINITY : u0;
            int   mi = ln;
            { const float v = s1m ? -INFINITY : u1; if (v > mv) { mv = v; mi = 64 + ln; } }
            { const float v = s2m ? -INFINITY : u2; if (v > mv) { mv = v; mi = 128 + ln; } }
            { const float v = s3m ? -INFINITY : u3; if (v > mv) { mv = v; mi = 192 + ln; } }
            float u4 = 0.f;
            if (ln == 0) {
                u4 = plL[0][e][256] + db4;
                const float v = s4m ? -INFINITY : u4;
                if (v > mv) { mv = v; mi = 256; }
            }
            // DPP argmax reduce (max value, smallest index on ties) -> lane 63
            AMAX64();
            const int   a   = __builtin_amdgcn_readlane(mi, 63);
            const float mvU = __builtin_bit_cast(float,
                                __builtin_amdgcn_readlane(__builtin_bit_cast(int, mv), 63));
            // gi loads for gate(t) ASAP (L2 latency hides under exp sum)
            {
                const float* gp2 = giT + a * 192;
                gi_r = gp2[ln]; gi_z = gp2[64 + ln]; gi_n = gp2[128 + ln];
            }
            // softmax denominator (feeds lp only)
            float S = 0.f;
            if (!s0m) S += __expf((u0 - mvU) * invT);
            if (!s1m) S += __expf((u1 - mvU) * invT);
            if (!s2m) S += __expf((u2 - mvU) * invT);
            if (!s3m) S += __expf((u3 - mvU) * invT);
            if (ln == 0 && !s4m) S += __expf((u4 - mvU) * invT);
            SUM64(S);
            const float Su = __builtin_bit_cast(float,
                                __builtin_amdgcn_readlane(__builtin_bit_cast(int, S), 63));
            // state update (registers, replicated consistently per wave)
            const bool wasdone = done;
            if (a == EOS_TOK) done = true;
            if ((a & 63) == ln) {
                if (a < 64) s0m = true; else if (a < 128) s1m = true;
                else if (a < 192) s2m = true; else if (a < 256) s3m = true;
                else s4m = true;
            }
            if (ln == 0 && m == 0) {
                const int b = b0 + e;
                out_act[b * L_MAX + (t - 1)] = (float)a;
                out_lp [b * L_MAX + (t - 1)] = wasdone ? 0.f : -__logf(Su);
                out_val[b * L_MAX + (t - 1)] = wasdone ? 0.f : 1.f;
            }
        }
        if (t == L_MAX) break;

        // ---- gate(t): thread (m, e, ln) updates one hidden unit ----
        {
            const float hr = ghL[m][e][ln];
            const float hz = ghL[m][e][64 + ln];
            const float hn = ghL[m][e][128 + ln];
            const float hp = hbuf[m][e][ln];
            const float r  = 1.f / (1.f + expf(-(gi_r + hr)));
            const float z  = 1.f / (1.f + expf(-(gi_z + hz)));
            const float n  = tanhf(gi_n + r * hn);
            const float h2 = (1.f - z) * n + z * hp;
            hbuf[m][e][ln] = h2;
            hsL[e][m * 64 + ln] = h2 * (1.f + ga) + be;
        }
        __syncthreads();   // B1: hbuf(t), hsL(t) ready

        // ================= P2: matvecs (reuse-2, asm pk_fma) ===============
        // film prefetch for t+1
        {
            const int tn = (t + 1 < L_MAX) ? t + 1 : L_MAX - 1;
            const float2 f = *(const float2*)&filmT[tn * 256 + (m * 64 + ln) * 2];
            ga = f.x; be = f.y;
        }
        if (isDec) {
            v2f a0 = {0,0}, a1 = {0,0}, a2 = {0,0}, a3 = {0,0};
            const int hb = dh * 64;
            #pragma unroll
            for (int jj = 0; jj < 16; ++jj) {
                const float4 x0 = *(const float4*)&hsL[0][hb + 4 * jj];
                const float4 x1 = *(const float4*)&hsL[1][hb + 4 * jj];
                const float4 x2 = *(const float4*)&hsL[2][hb + 4 * jj];
                const float4 x3 = *(const float4*)&hsL[3][hb + 4 * jj];
                const v2f w0 = wreg[4*jj], w1 = wreg[4*jj+1], w2 = wreg[4*jj+2], w3 = wreg[4*jj+3];
                v2f p;
                p = (v2f){x0.x, x0.y}; PK_LO(a0, w0, p); PK_HI(a0, w1, p);
                p = (v2f){x0.z, x0.w}; PK_LO(a0, w2, p); PK_HI(a0, w3, p);
                p = (v2f){x1.x, x1.y}; PK_LO(a1, w0, p); PK_HI(a1, w1, p);
                p = (v2f){x1.z, x1.w}; PK_LO(a1, w2, p); PK_HI(a1, w3, p);
                p = (v2f){x2.x, x2.y}; PK_LO(a2, w0, p); PK_HI(a2, w1, p);
                p = (v2f){x2.z, x2.w}; PK_LO(a2, w2, p); PK_HI(a2, w3, p);
                p = (v2f){x3.x, x3.y}; PK_LO(a3, w0, p); PK_HI(a3, w1, p);
                p = (v2f){x3.z, x3.w}; PK_LO(a3, w2, p); PK_HI(a3, w3, p);
            }
            *(v2f*)&plL[dh][0][2 * dq] = a0;
            *(v2f*)&plL[dh][1][2 * dq] = a1;
            *(v2f*)&plL[dh][2][2 * dq] = a2;
            *(v2f*)&plL[dh][3][2 * dq] = a3;
        } else if (isGru) {
            v2f a0 = bias2, a1 = bias2, a2 = bias2, a3 = bias2;
            #pragma unroll
            for (int jj = 0; jj < 16; ++jj) {
                const float4 x0 = *(const float4*)&hbuf[gm][0][4 * jj];
                const float4 x1 = *(const float4*)&hbuf[gm][1][4 * jj];
                const float4 x2 = *(const float4*)&hbuf[gm][2][4 * jj];
                const float4 x3 = *(const float4*)&hbuf[gm][3][4 * jj];
                const v2f w0 = wreg[4*jj], w1 = wreg[4*jj+1], w2 = wreg[4*jj+2], w3 = wreg[4*jj+3];
                v2f p;
                p = (v2f){x0.x, x0.y}; PK_LO(a0, w0, p); PK_HI(a0, w1, p);
                p = (v2f){x0.z, x0.w}; PK_LO(a0, w2, p); PK_HI(a0, w3, p);
                p = (v2f){x1.x, x1.y}; PK_LO(a1, w0, p); PK_HI(a1, w1, p);
                p = (v2f){x1.z, x1.w}; PK_LO(a1, w2, p); PK_HI(a1, w3, p);
                p = (v2f){x2.x, x2.y}; PK_LO(a2, w0, p); PK_HI(a2, w1, p);
                p = (v2f){x2.z, x2.w}; PK_LO(a2, w2, p); PK_HI(a2, w3, p);
                p = (v2f){x3.x, x3.y}; PK_LO(a3, w0, p); PK_HI(a3, w1, p);
                p = (v2f){x3.z, x3.w}; PK_LO(a3, w2, p); PK_HI(a3, w3, p);
            }
            *(v2f*)&ghL[gm][0][2 * gp] = a0;
            *(v2f*)&ghL[gm][1][2 * gp] = a1;
            *(v2f*)&ghL[gm][2][2 * gp] = a2;
            *(v2f*)&ghL[gm][3][2 * gp] = a3;
        } else if (isEos) {
            float t0, t1, t2, t3;
            {
                const float4 p0 = *(const float4*)&hsL[0][8 * ec];
                const float4 p1 = *(const float4*)&hsL[0][8 * ec + 4];
                t0 = p0.x*wreg[0].x + p0.y*wreg[0].y + p0.z*wreg[1].x + p0.w*wreg[1].y
                   + p1.x*wreg[2].x + p1.y*wreg[2].y + p1.z*wreg[3].x + p1.w*wreg[3].y;
            }
            {
                const float4 p0 = *(const float4*)&hsL[1][8 * ec];
                const float4 p1 = *(const float4*)&hsL[1][8 * ec + 4];
                t1 = p0.x*wreg[0].x + p0.y*wreg[0].y + p0.z*wreg[1].x + p0.w*wreg[1].y
                   + p1.x*wreg[2].x + p1.y*wreg[2].y + p1.z*wreg[3].x + p1.w*wreg[3].y;
            }
            {
                const float4 p0 = *(const float4*)&hsL[2][8 * ec];
                const float4 p1 = *(const float4*)&hsL[2][8 * ec + 4];
                t2 = p0.x*wreg[0].x + p0.y*wreg[0].y + p0.z*wreg[1].x + p0.w*wreg[1].y
                   + p1.x*wreg[2].x + p1.y*wreg[2].y + p1.z*wreg[3].x + p1.w*wreg[3].y;
            }
            {
                const float4 p0 = *(const float4*)&hsL[3][8 * ec];
                const float4 p1 = *(const float4*)&hsL[3][8 * ec + 4];
                t3 = p0.x*wreg[0].x + p0.y*wreg[0].y + p0.z*wreg[1].x + p0.w*wreg[1].y
                   + p1.x*wreg[2].x + p1.y*wreg[2].y + p1.z*wreg[3].x + p1.w*wreg[3].y;
            }
            // 16-lane DPP row sum; totals land in lane 15 (ec == 15)
            SUM16(t0); SUM16(t1); SUM16(t2); SUM16(t3);
            if (ec == 15) {
                plL[0][0][256] = t0; plL[0][1][256] = t1;
                plL[0][2][256] = t2; plL[0][3][256] = t3;
                plL[1][0][256] = 0.f; plL[1][1][256] = 0.f;
                plL[1][2][256] = 0.f; plL[1][3][256] = 0.f;
            }
        }
        __syncthreads();   // B2: plL(t), ghL(t+1) ready
    }
}

extern "C" void kernel_launch(void* const* d_in, const int* in_sizes, int n_in,
                              void* d_out, int out_size, void* d_ws, size_t ws_size,
                              hipStream_t stream)
{
    const int*   step        = (const int*)  d_in[0];
    const float* token_embed = (const float*)d_in[2];
    const float* step_table  = (const float*)d_in[3];
    const float* w_ih_f = (const float*)d_in[4];
    const float* w_hh_f = (const float*)d_in[5];
    const float* b_ih_f = (const float*)d_in[6];
    const float* b_hh_f = (const float*)d_in[7];
    const float* w_ih_b = (const float*)d_in[8];
    const float* w_hh_b = (const float*)d_in[9];
    const float* b_ih_b = (const float*)d_in[10];
    const float* b_hh_b = (const float*)d_in[11];
    const float* film_w = (const float*)d_in[12];
    const float* film_b = (const float*)d_in[13];
    const float* dec_w  = (const float*)d_in[14];
    const float* dec_b  = (const float*)d_in[15];
    float* ws   = (float*)d_ws;
    float* outp = (float*)d_out;

    aag_precompute<<<TOTAL_PRE / 256, 256, 0, stream>>>(
        token_embed, step_table, w_ih_f, b_ih_f, w_ih_b, b_ih_b,
        film_w, film_b, ws);
    aag_decode<<<256, 512, 0, stream>>>(
        step, w_hh_f, b_hh_f, w_hh_b, b_hh_b, dec_w, dec_b, ws, outp);
}